// Round 1
// baseline (144.242 us; speedup 1.0000x reference)
//
#include <hip/hip_runtime.h>
#include <hip/hip_bf16.h>

#define B_ 64
#define J_ 2048
#define I_ 16
#define K_ 32
#define D_ 16
#define KD 512            // K_*D_
#define WPB 64            // waves per batch element in routing kernels
#define JCH (J_ / WPB)    // 32 j's per wave

__device__ __forceinline__ float bf2f(unsigned int bits16) {
  unsigned int u = bits16 << 16;
  return __builtin_bit_cast(float, u);
}
__device__ __forceinline__ unsigned short f2bf(float f) {
  unsigned int u = __builtin_bit_cast(unsigned int, f);
  u = u + 0x7fffu + ((u >> 16) & 1u);   // round-to-nearest-even
  return (unsigned short)(u >> 16);
}

// ---------------- K1: u_hat[b][j][k][d] (bf16) = sum_i inputs[b,j,i] * W[k,j,d,i]
// one block per j; thread t owns kd = 2t, 2t+1; W slice (32 floats) lives in registers
// and is reused across all 64 batch elements.
__global__ __launch_bounds__(256) void k_uhat(const float* __restrict__ inp,
                                              const float* __restrict__ W,
                                              unsigned int* __restrict__ uhat /* packed bf16x2 */) {
  const int j = blockIdx.x;
  const int t = threadIdx.x;
  const int kd0 = 2 * t;
  const int k0 = kd0 >> 4;
  const int d0 = kd0 & 15;
  // W[k,j,d,i] at ((k*J_ + j)*16 + d)*16 + i ; for fixed (k0,j) the 32 floats
  // covering (d0,i=0..15),(d0+1,i=0..15) are contiguous.
  const float* wp = W + (size_t)k0 * (J_ * 256) + (size_t)j * 256 + d0 * 16;
  float w[32];
#pragma unroll
  for (int q = 0; q < 8; ++q)
    *reinterpret_cast<float4*>(&w[4 * q]) = *reinterpret_cast<const float4*>(wp + 4 * q);

  __shared__ float in_lds[B_ * I_];
  for (int e = t; e < B_ * I_; e += 256) {
    int b = e >> 4, i = e & 15;
    in_lds[e] = inp[(size_t)(b * J_ + j) * I_ + i];
  }
  __syncthreads();

  for (int b = 0; b < B_; ++b) {
    float a0 = 0.f, a1 = 0.f;
#pragma unroll
    for (int i = 0; i < 16; ++i) {
      float x = in_lds[b * 16 + i];          // LDS broadcast (same addr all lanes)
      a0 = fmaf(x, w[i], a0);
      a1 = fmaf(x, w[16 + i], a1);
    }
    unsigned int pk = (unsigned int)f2bf(a0) | ((unsigned int)f2bf(a1) << 16);
    uhat[(size_t)(b * J_ + j) * 256 + t] = pk;   // coalesced: stride-1 in t
  }
}

// ---------------- RK: one routing sweep over u_hat.
// wave = (b, j-chunk of 32). lane owns 8 contiguous (k,d): kd0 = lane*8, k = lane>>1.
// MODE 0: c = 1/32 (softmax of zeros).  MODE 1: logits = o0 . u_hat.
// MODE 2: logits = (o0+o1) . u_hat ; also writes c to d_out via LDS transpose.
template <int MODE>
__global__ __launch_bounds__(256) void k_route(const unsigned int* __restrict__ uhat,
                                               const float* __restrict__ osum,
                                               float* __restrict__ spart,
                                               float* __restrict__ outp) {
  const int t = threadIdx.x;
  const int wave = t >> 6, lane = t & 63;
  const int gw = blockIdx.x * 4 + wave;       // 0 .. B_*WPB-1
  const int b = gw / WPB;
  const int lw = gw % WPB;
  const int kd0 = lane * 8;
  const int k = lane >> 1;

  __shared__ float cbuf[(MODE == 2) ? 4 * K_ * (JCH + 1) : 4];

  float os[8];
  if constexpr (MODE >= 1) {
#pragma unroll
    for (int q = 0; q < 8; ++q) os[q] = osum[b * KD + kd0 + q];
  }
  float acc[8] = {0.f, 0.f, 0.f, 0.f, 0.f, 0.f, 0.f, 0.f};

  const int j0 = lw * JCH;
  const uint4* up = reinterpret_cast<const uint4*>(uhat) + (size_t)(b * J_ + j0) * 64 + lane;
  uint4 nxt = *up;                            // 16B/lane, wave reads 1KB contiguous
  for (int jj = 0; jj < JCH; ++jj) {
    uint4 cur = nxt;
    if (jj + 1 < JCH) nxt = up[(size_t)(jj + 1) * 64];
    float u[8];
    u[0] = bf2f(cur.x & 0xffffu); u[1] = bf2f(cur.x >> 16);
    u[2] = bf2f(cur.y & 0xffffu); u[3] = bf2f(cur.y >> 16);
    u[4] = bf2f(cur.z & 0xffffu); u[5] = bf2f(cur.z >> 16);
    u[6] = bf2f(cur.w & 0xffffu); u[7] = bf2f(cur.w >> 16);

    float c;
    if constexpr (MODE == 0) {
      c = 1.0f / 32.0f;
    } else {
      float p = 0.f;
#pragma unroll
      for (int q = 0; q < 8; ++q) p = fmaf(os[q], u[q], p);
      p += __shfl_xor(p, 1);                  // lane pair -> full dot for k = lane>>1
      float m = p;
#pragma unroll
      for (int s = 2; s <= 32; s <<= 1) m = fmaxf(m, __shfl_xor(m, s));
      float e = __expf(p - m);
      float S = e;
#pragma unroll
      for (int s = 2; s <= 32; s <<= 1) S += __shfl_xor(S, s);
      c = e / S;
    }
    if constexpr (MODE == 2) {
      if ((lane & 1) == 0) cbuf[wave * (K_ * (JCH + 1)) + k * (JCH + 1) + jj] = c;
    }
#pragma unroll
    for (int q = 0; q < 8; ++q) acc[q] = fmaf(c, u[q], acc[q]);
  }

  if constexpr (MODE == 2) {
    __syncthreads();
    // write c rows: K_=32 rows x JCH=32 cols per wave; 2 rows per pass
    const int col = lane & 31, rhalf = lane >> 5;
#pragma unroll
    for (int pass = 0; pass < 16; ++pass) {
      int r = pass * 2 + rhalf;
      outp[(size_t)(b * K_ + r) * 2064 + 16 + j0 + col] =
          cbuf[wave * (K_ * (JCH + 1)) + r * (JCH + 1) + col];
    }
  }

#pragma unroll
  for (int q = 0; q < 8; ++q)
    spart[(size_t)(b * WPB + lw) * KD + kd0 + q] = acc[q];
}

// ---------------- SQ: reduce partials -> s, squash -> outputs; accumulate osum.
// one wave per (b,k). lane: d = lane&15, partial-group pg = lane>>4.
__global__ __launch_bounds__(256) void k_squash(const float* __restrict__ spart,
                                                float* __restrict__ osum,
                                                float* __restrict__ outp,
                                                int first, int final_) {
  const int t = threadIdx.x;
  const int wave = t >> 6, lane = t & 63;
  const int gw = blockIdx.x * 4 + wave;   // 0..B_*K_-1
  const int b = gw >> 5, k = gw & 31;
  const int d = lane & 15, pg = lane >> 4;
  float s = 0.f;
  for (int p = pg; p < WPB; p += 4)
    s += spart[(size_t)(b * WPB + p) * KD + k * D_ + d];
  s += __shfl_xor(s, 16);
  s += __shfl_xor(s, 32);
  float ss = s * s;
  ss += __shfl_xor(ss, 1); ss += __shfl_xor(ss, 2);
  ss += __shfl_xor(ss, 4); ss += __shfl_xor(ss, 8);
  float scale = (ss / (1.f + ss)) * rsqrtf(ss + 1e-7f);
  float ov = scale * s;
  if (lane < 16) {
    if (final_) {
      outp[(size_t)(b * K_ + k) * 2064 + d] = ov;
    } else {
      float prev = first ? 0.f : osum[(b * K_ + k) * D_ + d];
      osum[(b * K_ + k) * D_ + d] = prev + ov;
    }
  }
}

extern "C" void kernel_launch(void* const* d_in, const int* in_sizes, int n_in,
                              void* d_out, int out_size, void* d_ws, size_t ws_size,
                              hipStream_t stream) {
  const float* inp = (const float*)d_in[0];   // [64,2048,16]
  const float* W   = (const float*)d_in[1];   // [32,2048,16,16]
  float* outp = (float*)d_out;                // [64,32,2064]
  char* ws = (char*)d_ws;
  // ws layout: uhat bf16 (128 MiB) | spart (8 MiB) | osum (128 KiB)  => ~136.1 MiB
  unsigned int* uhat = (unsigned int*)ws;
  float* spart = (float*)(ws + (size_t)134217728);
  float* osum  = (float*)(ws + (size_t)134217728 + 8388608);

  k_uhat<<<J_, 256, 0, stream>>>(inp, W, uhat);
  k_route<0><<<B_ * WPB / 4, 256, 0, stream>>>(uhat, nullptr, spart, nullptr);
  k_squash<<<B_ * K_ / 4, 256, 0, stream>>>(spart, osum, outp, 1, 0);
  k_route<1><<<B_ * WPB / 4, 256, 0, stream>>>(uhat, osum, spart, nullptr);
  k_squash<<<B_ * K_ / 4, 256, 0, stream>>>(spart, osum, outp, 0, 0);
  k_route<2><<<B_ * WPB / 4, 256, 0, stream>>>(uhat, osum, spart, outp);
  k_squash<<<B_ * K_ / 4, 256, 0, stream>>>(spart, osum, outp, 0, 1);
}